// Round 1
// 1764.325 us; speedup vs baseline: 1.1494x; 1.1494x over previous
//
#include <hip/hip_runtime.h>
#include <cstdint>
#include <cstddef>

typedef unsigned short ushort_t;
typedef __attribute__((ext_vector_type(8))) short short8;   // 8 x bf16 (4 VGPRs)
typedef __attribute__((ext_vector_type(4))) float f32x4;    // MFMA accumulator

#define S_LEN 1024
#define HDIM 3584
#define N_HEADS 28
#define N_KV 4
#define HEAD_DIM 128
#define GQA_RATIO 7
#define INTER_DIM 18944
#define QKV_DIM 4608   // 3584 + 512 + 512 (fused q|k|v output columns)

__device__ __forceinline__ ushort_t f2bf(float f) {
  union { float f; uint32_t u; } x; x.f = f;
  uint32_t u = x.u;
  uint32_t r = (u + 0x7FFFu + ((u >> 16) & 1u)) >> 16;  // RTNE
  return (ushort_t)r;
}
__device__ __forceinline__ float bf2f(ushort_t b) {
  union { uint32_t u; float f; } x; x.u = ((uint32_t)b) << 16;
  return x.f;
}

// async global->LDS DMA, 16B per lane. LDS dest is WAVE-UNIFORM base; HW adds lane*16.
__device__ __forceinline__ void load_lds_128(const ushort_t* g, ushort_t* l) {
  __builtin_amdgcn_global_load_lds(
      (const __attribute__((address_space(1))) uint32_t*)g,
      (__attribute__((address_space(3))) uint32_t*)(uint32_t)(uintptr_t)l,
      16, 0, 0);
}

// ---------------- transpose fp32 [K][N] -> bf16 [N][K] ----------------
__global__ __launch_bounds__(256) void transpose_bf16_kernel(
    const float* __restrict__ W, ushort_t* __restrict__ Wt, int K, int N) {
  __shared__ float tile[64][65];
  int k0 = blockIdx.y * 64, n0 = blockIdx.x * 64;
  int t = threadIdx.x;
#pragma unroll
  for (int i = 0; i < 4; i++) {
    int c = i * 256 + t;
    int kr = c >> 4, nc = (c & 15) * 4;
    float4 v = *reinterpret_cast<const float4*>(W + (size_t)(k0 + kr) * N + n0 + nc);
    tile[kr][nc] = v.x; tile[kr][nc + 1] = v.y; tile[kr][nc + 2] = v.z; tile[kr][nc + 3] = v.w;
  }
  __syncthreads();
#pragma unroll
  for (int i = 0; i < 2; i++) {
    int c = i * 256 + t;
    int n = c >> 3, k8 = (c & 7) * 8;
    ushort_t tmp[8];
#pragma unroll
    for (int j = 0; j < 8; j++) tmp[j] = f2bf(tile[k8 + j][n]);
    uint4 pack;
    pack.x = (uint32_t)tmp[0] | ((uint32_t)tmp[1] << 16);
    pack.y = (uint32_t)tmp[2] | ((uint32_t)tmp[3] << 16);
    pack.z = (uint32_t)tmp[4] | ((uint32_t)tmp[5] << 16);
    pack.w = (uint32_t)tmp[6] | ((uint32_t)tmp[7] << 16);
    *reinterpret_cast<uint4*>(Wt + (size_t)(n0 + n) * K + k0 + k8) = pack;
  }
}

// ---------------- RMSNorm: fp32 in -> bf16 out ----------------
__global__ __launch_bounds__(256) void rmsnorm_kernel(
    const float* __restrict__ x, const float* __restrict__ w, ushort_t* __restrict__ out) {
  int row = blockIdx.x;
  const float* xr = x + (size_t)row * HDIM;
  float ss = 0.f;
  for (int i = threadIdx.x; i < HDIM / 4; i += 256) {
    float4 v = reinterpret_cast<const float4*>(xr)[i];
    ss += v.x * v.x + v.y * v.y + v.z * v.z + v.w * v.w;
  }
#pragma unroll
  for (int off = 32; off > 0; off >>= 1) ss += __shfl_xor(ss, off, 64);
  __shared__ float red[4];
  if ((threadIdx.x & 63) == 0) red[threadIdx.x >> 6] = ss;
  __syncthreads();
  float total = red[0] + red[1] + red[2] + red[3];
  float rs = rsqrtf(total / (float)HDIM + 1e-6f);
  ushort_t* orow = out + (size_t)row * HDIM;
  for (int i = threadIdx.x; i < HDIM / 4; i += 256) {
    float4 v = reinterpret_cast<const float4*>(xr)[i];
    float4 g = reinterpret_cast<const float4*>(w)[i];
    uint2 pk;
    pk.x = (uint32_t)f2bf(v.x * rs * g.x) | ((uint32_t)f2bf(v.y * rs * g.y) << 16);
    pk.y = (uint32_t)f2bf(v.z * rs * g.z) | ((uint32_t)f2bf(v.w * rs * g.w) << 16);
    *reinterpret_cast<uint2*>(orow + i * 4) = pk;
  }
}

// ---------------- small copy / bias helpers ----------------
__global__ __launch_bounds__(256) void copy_f32_kernel(
    const float* __restrict__ src, float* __restrict__ dst) {
  int i = blockIdx.x * 256 + threadIdx.x;
  reinterpret_cast<float4*>(dst)[i] = reinterpret_cast<const float4*>(src)[i];
}

__global__ __launch_bounds__(256) void concat_bias_kernel(
    const float* __restrict__ qb, const float* __restrict__ kb, const float* __restrict__ vb,
    float* __restrict__ out) {
  int i = blockIdx.x * 256 + threadIdx.x;
  if (i < QKV_DIM)
    out[i] = (i < HDIM) ? qb[i] : ((i < HDIM + 512) ? kb[i - HDIM] : vb[i - HDIM - 512]);
}

__global__ __launch_bounds__(256) void bias_broadcast_kernel(
    const float* __restrict__ bias, float* __restrict__ out) {
  int s = blockIdx.x;
  const float4* b4 = reinterpret_cast<const float4*>(bias);
  float4* o4 = reinterpret_cast<float4*>(out + (size_t)s * QKV_DIM);
  for (int i = threadIdx.x; i < QKV_DIM / 4; i += 256) o4[i] = b4[i];
}

// ---------------- RoPE + pack from fused QKV buffer [S][QKV_DIM] ----------------
__global__ __launch_bounds__(128) void rope_pack_kernel(
    const float* __restrict__ qf, const float* __restrict__ kf, const float* __restrict__ vf,
    const float* __restrict__ cosc, const float* __restrict__ sinc,
    ushort_t* __restrict__ q_bf, ushort_t* __restrict__ k_bf, ushort_t* __restrict__ v_t,
    float* __restrict__ out_k, float* __restrict__ out_v) {
  int s = blockIdx.x, hh = blockIdx.y, d = threadIdx.x;
  float c = cosc[s * HEAD_DIM + d], sn = sinc[s * HEAD_DIM + d];
  if (hh < N_HEADS) {
    const float* q = qf + (size_t)s * QKV_DIM + hh * HEAD_DIM;
    float v0 = q[d];
    float vr = (d < 64) ? -q[d + 64] : q[d - 64];
    float r = (v0 * c + vr * sn) * 0.08838834764831845f;  // fold 1/sqrt(128)
    q_bf[((size_t)hh * S_LEN + s) * HEAD_DIM + d] = f2bf(r);
  } else if (hh < N_HEADS + N_KV) {
    int kh = hh - N_HEADS;
    const float* k = kf + (size_t)s * QKV_DIM + kh * HEAD_DIM;
    float v0 = k[d];
    float vr = (d < 64) ? -k[d + 64] : k[d - 64];
    float r = v0 * c + vr * sn;
    size_t idx = ((size_t)kh * S_LEN + s) * HEAD_DIM + d;
    k_bf[idx] = f2bf(r);
    out_k[idx] = r;
  } else {
    int kh = hh - N_HEADS - N_KV;
    size_t idx = ((size_t)kh * S_LEN + s) * HEAD_DIM + d;
    float r = vf[(size_t)s * QKV_DIM + kh * HEAD_DIM + d];
    v_t[((size_t)kh * HEAD_DIM + d) * S_LEN + s] = f2bf(r);  // transposed for PV NT-GEMM
    out_v[idx] = r;
  }
}

// ---------------- causal softmax, in place on bf16 scores ----------------
__global__ __launch_bounds__(256) void softmax_kernel(ushort_t* __restrict__ sc) {
  int r = blockIdx.x, h = blockIdx.y;
  ushort_t* row = sc + ((size_t)h * S_LEN + r) * S_LEN;
  int valid = r + 1;
  float vals[4];
  float mx = -1e30f;
#pragma unroll
  for (int k = 0; k < 4; k++) {
    int j = threadIdx.x + k * 256;
    float x = (j < valid) ? bf2f(row[j]) : -1e30f;
    vals[k] = x;
    mx = fmaxf(mx, x);
  }
#pragma unroll
  for (int off = 32; off > 0; off >>= 1) mx = fmaxf(mx, __shfl_xor(mx, off, 64));
  __shared__ float red[4];
  int lane = threadIdx.x & 63, wid = threadIdx.x >> 6;
  if (lane == 0) red[wid] = mx;
  __syncthreads();
  mx = fmaxf(fmaxf(red[0], red[1]), fmaxf(red[2], red[3]));
  float sum = 0.f;
#pragma unroll
  for (int k = 0; k < 4; k++) {
    int j = threadIdx.x + k * 256;
    float e = (j < valid) ? __expf(vals[k] - mx) : 0.f;
    vals[k] = e;
    sum += e;
  }
#pragma unroll
  for (int off = 32; off > 0; off >>= 1) sum += __shfl_xor(sum, off, 64);
  __syncthreads();
  if (lane == 0) red[wid] = sum;
  __syncthreads();
  sum = red[0] + red[1] + red[2] + red[3];
  float inv = 1.f / sum;
#pragma unroll
  for (int k = 0; k < 4; k++) {
    int j = threadIdx.x + k * 256;
    row[j] = f2bf(vals[k] * inv);
  }
}

// ---------------- NT bf16 GEMM with global_load_lds staging + XOR-swizzled LDS ----------------
// LDS tile [128][64] bf16 unpadded; 16B col-block c stored at phys c ^ (row&7).
// EPI: 0 = +bias -> fp32 | 1 = scores bf16 (causal block skip) | 2 = PV bf16
//      3 = +residual -> fp32 | 4 = bf16 | 5 = silu(g)*c -> bf16 | 6 = +residual -> fp32
//      7 = fp32 atomic accumulate (split-K: blockIdx.z = K-chunk index, kchunk > 0)
template <int EPI>
__global__ __launch_bounds__(256) void gemm_nt(
    const ushort_t* __restrict__ A, const ushort_t* __restrict__ Bt, void* __restrict__ Cout,
    const float* __restrict__ aux0, const ushort_t* __restrict__ aux1,
    int M, int N, int K, int lda, int ldb, int ldc,
    long long sA, long long sB, int sBdiv, long long sC, int causal, int kchunk) {
  int m0 = blockIdx.y * 128, n0 = blockIdx.x * 128;
  if (EPI == 1 && n0 > m0 + 127) return;  // fully-masked causal block
  int z = blockIdx.z;
  const ushort_t* Ab = A + (size_t)z * sA;
  const ushort_t* Bb = Bt + (size_t)(z / sBdiv) * sB;

  int kbeg, kend;
  if (kchunk > 0) {            // split-K: z indexes the K-chunk (sA=sB=0 callers)
    kbeg = z * kchunk;
    kend = kbeg + kchunk;
  } else {
    kbeg = 0;
    kend = (causal == 2) ? (m0 + 128) : K;  // PV: P rows are 0 beyond m0+127
  }

  __shared__ __align__(16) ushort_t As[128 * 64];
  __shared__ __align__(16) ushort_t Bs[128 * 64];

  int t = threadIdx.x;
  int lane = t & 63, wid = t >> 6;
  int wm = (wid >> 1) * 64, wn = (wid & 1) * 64;
  int lr = lane & 15, lq = lane >> 4;

  // staging: issue q = wid*4+j covers rows q*8 .. q*8+7, lane -> row q*8 + (lane>>3),
  // phys col block = lane&7, logical col block = (lane&7) ^ ((lane>>3)&7)
  int rsub = lane >> 3;
  int clg = (lane & 7) ^ rsub;  // logical 16B col block this lane fetches
  const ushort_t* agp[4];
  const ushort_t* bgp[4];
#pragma unroll
  for (int j = 0; j < 4; j++) {
    int q = wid * 4 + j;
    int r = q * 8 + rsub;
    agp[j] = Ab + (size_t)(m0 + r) * lda + clg * 8;
    bgp[j] = Bb + (size_t)(n0 + r) * ldb + clg * 8;
  }

  f32x4 acc[4][4];
#pragma unroll
  for (int a = 0; a < 4; a++)
#pragma unroll
    for (int b = 0; b < 4; b++) acc[a][b] = (f32x4){0.f, 0.f, 0.f, 0.f};

  for (int k0 = kbeg; k0 < kend; k0 += 64) {
#pragma unroll
    for (int j = 0; j < 4; j++) {
      int q = wid * 4 + j;
      load_lds_128(agp[j] + k0, As + q * 512);
      load_lds_128(bgp[j] + k0, Bs + q * 512);
    }
    __syncthreads();  // drains vmcnt (incl. LDS-DMA) + barrier
#pragma unroll
    for (int kk = 0; kk < 2; kk++) {
      short8 af[4], bfr[4];
#pragma unroll
      for (int i = 0; i < 4; i++) {
        int ra = wm + i * 16 + lr;
        int ca = ((kk << 2) + lq) ^ (ra & 7);
        af[i] = *reinterpret_cast<const short8*>(&As[ra * 64 + ca * 8]);
        int rb = wn + i * 16 + lr;
        int cb = ((kk << 2) + lq) ^ (rb & 7);
        bfr[i] = *reinterpret_cast<const short8*>(&Bs[rb * 64 + cb * 8]);
      }
#pragma unroll
      for (int im = 0; im < 4; im++)
#pragma unroll
        for (int in = 0; in < 4; in++)
          acc[im][in] = __builtin_amdgcn_mfma_f32_16x16x32_bf16(af[im], bfr[in], acc[im][in], 0, 0, 0);
    }
    __syncthreads();
  }

#pragma unroll
  for (int im = 0; im < 4; im++) {
#pragma unroll
    for (int in = 0; in < 4; in++) {
      int n = n0 + wn + in * 16 + lr;
      float bias = (EPI == 0) ? aux0[n] : 0.f;
#pragma unroll
      for (int rr = 0; rr < 4; rr++) {
        int m = m0 + wm + im * 16 + lq * 4 + rr;
        float v = acc[im][in][rr];
        size_t cidx = (EPI == 7) ? ((size_t)m * ldc + n) : ((size_t)z * sC + (size_t)m * ldc + n);
        if (EPI == 0) {
          ((float*)Cout)[cidx] = v + bias;
        } else if (EPI == 1 || EPI == 2 || EPI == 4) {
          ((ushort_t*)Cout)[cidx] = f2bf(v);
        } else if (EPI == 3 || EPI == 6) {
          ((float*)Cout)[cidx] = v + aux0[(size_t)m * ldc + n];
        } else if (EPI == 5) {
          float g = bf2f(aux1[(size_t)m * ldc + n]);
          float sg = g / (1.f + __expf(-g));
          ((ushort_t*)Cout)[cidx] = f2bf(sg * v);
        } else if (EPI == 7) {
          unsafeAtomicAdd((float*)Cout + cidx, v);  // global_atomic_add_f32
        }
      }
    }
  }
}

extern "C" void kernel_launch(void* const* d_in, const int* in_sizes, int n_in,
                              void* d_out, int out_size, void* d_ws, size_t ws_size,
                              hipStream_t stream) {
  const float* hidden = (const float*)d_in[0];
  const float* ln0_w  = (const float*)d_in[3];
  const float* ln1_w  = (const float*)d_in[4];
  const float* q_w    = (const float*)d_in[5];
  const float* q_b    = (const float*)d_in[6];
  const float* k_w    = (const float*)d_in[7];
  const float* k_b    = (const float*)d_in[8];
  const float* v_w    = (const float*)d_in[9];
  const float* v_b    = (const float*)d_in[10];
  const float* o_w    = (const float*)d_in[11];
  const float* gate_w = (const float*)d_in[12];
  const float* up_w   = (const float*)d_in[13];
  const float* down_w = (const float*)d_in[14];
  const float* cosc   = (const float*)d_in[15];
  const float* sinc   = (const float*)d_in[16];

  float* out0  = (float*)d_out;
  float* out_k = out0 + (size_t)S_LEN * HDIM;
  float* out_v = out_k + (size_t)N_KV * S_LEN * HEAD_DIM;

  char* wsp = (char*)d_ws;
  auto alloc = [&](size_t bytes) -> void* {
    void* p = (void*)wsp;
    wsp += (bytes + 255) & ~(size_t)255;
    return p;
  };
  ushort_t* wt   = (ushort_t*)alloc((size_t)INTER_DIM * HDIM * 2);
  ushort_t* xn   = (ushort_t*)alloc((size_t)S_LEN * HDIM * 2);
  float*    qkvf = (float*)alloc((size_t)S_LEN * QKV_DIM * 4);
  float*    qkvb = (float*)alloc((size_t)QKV_DIM * 4);
  ushort_t* q_bf = (ushort_t*)alloc((size_t)N_HEADS * S_LEN * HEAD_DIM * 2);
  ushort_t* k_bf = (ushort_t*)alloc((size_t)N_KV * S_LEN * HEAD_DIM * 2);
  ushort_t* v_t  = (ushort_t*)alloc((size_t)N_KV * S_LEN * HEAD_DIM * 2);
  ushort_t* sc   = (ushort_t*)alloc((size_t)N_HEADS * S_LEN * S_LEN * 2);
  ushort_t* attn = (ushort_t*)alloc((size_t)S_LEN * HDIM * 2);
  float*    hs   = (float*)alloc((size_t)S_LEN * HDIM * 4);
  ushort_t* y_bf = (ushort_t*)alloc((size_t)S_LEN * HDIM * 2);
  ushort_t* g_bf = (ushort_t*)alloc((size_t)S_LEN * INTER_DIM * 2);

  dim3 blk256(256), blk128(128);

  rmsnorm_kernel<<<dim3(S_LEN), blk256, 0, stream>>>(hidden, ln0_w, xn);

  // --- fused QKV projection: Wt rows 0..3583 = q, 3584..4095 = k, 4096..4607 = v ---
  transpose_bf16_kernel<<<dim3(HDIM / 64, HDIM / 64), blk256, 0, stream>>>(q_w, wt, HDIM, HDIM);
  transpose_bf16_kernel<<<dim3(512 / 64, HDIM / 64), blk256, 0, stream>>>(k_w, wt + (size_t)HDIM * HDIM, HDIM, 512);
  transpose_bf16_kernel<<<dim3(512 / 64, HDIM / 64), blk256, 0, stream>>>(v_w, wt + (size_t)(HDIM + 512) * HDIM, HDIM, 512);
  concat_bias_kernel<<<dim3((QKV_DIM + 255) / 256), blk256, 0, stream>>>(q_b, k_b, v_b, qkvb);
  bias_broadcast_kernel<<<dim3(S_LEN), blk256, 0, stream>>>(qkvb, qkvf);
  // split-K x2: K=3584 -> 2 chunks of 1792 (28 k-steps); grid 36*8*2 = 576 blocks
  gemm_nt<7><<<dim3(QKV_DIM / 128, S_LEN / 128, 2), blk256, 0, stream>>>(
      xn, wt, qkvf, nullptr, nullptr, S_LEN, QKV_DIM, HDIM, HDIM, HDIM, QKV_DIM,
      0, 0, 1, 0, 0, HDIM / 2);

  rope_pack_kernel<<<dim3(S_LEN, N_HEADS + 2 * N_KV), blk128, 0, stream>>>(
      qkvf, qkvf + HDIM, qkvf + HDIM + 512, cosc, sinc, q_bf, k_bf, v_t, out_k, out_v);

  gemm_nt<1><<<dim3(S_LEN / 128, S_LEN / 128, N_HEADS), blk256, 0, stream>>>(
      q_bf, k_bf, sc, nullptr, nullptr, S_LEN, S_LEN, HEAD_DIM, HEAD_DIM, HEAD_DIM, S_LEN,
      (long long)S_LEN * HEAD_DIM, (long long)S_LEN * HEAD_DIM, GQA_RATIO,
      (long long)S_LEN * S_LEN, 1, 0);

  softmax_kernel<<<dim3(S_LEN, N_HEADS), blk256, 0, stream>>>(sc);

  gemm_nt<2><<<dim3(HEAD_DIM / 128, S_LEN / 128, N_HEADS), blk256, 0, stream>>>(
      sc, v_t, attn, nullptr, nullptr, S_LEN, HEAD_DIM, S_LEN, S_LEN, S_LEN, HDIM,
      (long long)S_LEN * S_LEN, (long long)S_LEN * HEAD_DIM, GQA_RATIO, (long long)HEAD_DIM, 2, 0);

  // --- O projection, split-K x2, residual pre-copied ---
  transpose_bf16_kernel<<<dim3(HDIM / 64, HDIM / 64), blk256, 0, stream>>>(o_w, wt, HDIM, HDIM);
  copy_f32_kernel<<<dim3(S_LEN * HDIM / 4 / 256), blk256, 0, stream>>>(hidden, hs);
  gemm_nt<7><<<dim3(HDIM / 128, S_LEN / 128, 2), blk256, 0, stream>>>(
      attn, wt, hs, nullptr, nullptr, S_LEN, HDIM, HDIM, HDIM, HDIM, HDIM,
      0, 0, 1, 0, 0, HDIM / 2);

  rmsnorm_kernel<<<dim3(S_LEN), blk256, 0, stream>>>(hs, ln1_w, y_bf);

  transpose_bf16_kernel<<<dim3(INTER_DIM / 64, HDIM / 64), blk256, 0, stream>>>(gate_w, wt, HDIM, INTER_DIM);
  gemm_nt<4><<<dim3(INTER_DIM / 128, S_LEN / 128, 1), blk256, 0, stream>>>(
      y_bf, wt, g_bf, nullptr, nullptr, S_LEN, INTER_DIM, HDIM, HDIM, HDIM, INTER_DIM, 0, 0, 1, 0, 0, 0);
  transpose_bf16_kernel<<<dim3(INTER_DIM / 64, HDIM / 64), blk256, 0, stream>>>(up_w, wt, HDIM, INTER_DIM);
  gemm_nt<5><<<dim3(INTER_DIM / 128, S_LEN / 128, 1), blk256, 0, stream>>>(
      y_bf, wt, g_bf, nullptr, g_bf, S_LEN, INTER_DIM, HDIM, HDIM, HDIM, INTER_DIM, 0, 0, 1, 0, 0, 0);

  // --- down projection, split-K x4 (K=18944 -> 4 chunks of 4736 = 74 k-steps), residual pre-copied ---
  transpose_bf16_kernel<<<dim3(HDIM / 64, INTER_DIM / 64), blk256, 0, stream>>>(down_w, wt, INTER_DIM, HDIM);
  copy_f32_kernel<<<dim3(S_LEN * HDIM / 4 / 256), blk256, 0, stream>>>(hs, out0);
  gemm_nt<7><<<dim3(HDIM / 128, S_LEN / 128, 4), blk256, 0, stream>>>(
      g_bf, wt, out0, nullptr, nullptr, S_LEN, HDIM, INTER_DIM, INTER_DIM, INTER_DIM, HDIM,
      0, 0, 1, 0, 0, INTER_DIM / 4);
}